// Round 7
// baseline (73.333 us; speedup 1.0000x reference)
//
#include <hip/hip_runtime.h>

#define IMG_H 224
#define IMG_W 224
#define NPIX (IMG_H * IMG_W)        // 50176
#define NG 1024
#define TILE 16
#define TXN (IMG_W / TILE)          // 14
#define TYN (IMG_H / TILE)          // 14  -> 196 blocks
#define GPT (NG / 256)              // 4 gaussians per thread in prep phase

#define K_EXP  -0.72134752044448170368f   // -0.5 * log2(e)
#define ELIM   -21.640425613334451f       // 30 * K_EXP  (min(dist,30))
#define W15     3.0590232050182579e-07f   // exp(-15) = 2^ELIM

// Single fused kernel: per-block param compute + tile cull (wave-aggregated LDS
// compaction) + raster. Exactness: outside the {dist<=30} ellipse the clamped
// weight is exactly exp(-15)=W15, so unlisted gaussians contribute W15*(a*color),
// covered by the background term W15*S; listed ones accumulate (w - W15).
__global__ __launch_bounds__(256) void fused_raster_kernel(
    const float* __restrict__ alpha,
    const float* __restrict__ color,
    const float* __restrict__ offset,
    const float* __restrict__ scale,
    const float* __restrict__ rotation,
    const float* __restrict__ basep,
    const float* __restrict__ iw,
    float* __restrict__ out)
{
    __shared__ float4 list[NG * 2];   // 32 KiB: 2 x float4 per accepted gaussian
    __shared__ float  sred[4][3];
    __shared__ int    cnt;

    const int tid = (int)threadIdx.x;
    if (tid == 0) cnt = 0;
    __syncthreads();

    const int bx0 = blockIdx.x * TILE;
    const int by0 = blockIdx.y * TILE;
    const float txmin = (float)bx0, txmax = (float)(bx0 + TILE - 1);
    const float tymin = (float)by0, tymax = (float)(by0 + TILE - 1);

    const float2* __restrict__ off2   = (const float2*)offset;
    const float2* __restrict__ scale2 = (const float2*)scale;
    const float2* __restrict__ base2  = (const float2*)basep;

    const int lane = tid & 63;
    float sr = 0.f, sg = 0.f, sb = 0.f;

    #pragma unroll
    for (int k = 0; k < GPT; ++k) {
        const int g = tid + k * 256;                 // coalesced across threads
        const float2 of = off2[g];
        const float2 bp = base2[g];
        const float2 sc = scale2[g];
        const float rot = rotation[g];
        const float a   = alpha[g] * iw[g];

        float cx = fminf(fmaxf(bp.x + of.x, 0.f), 224.f);
        float cy = fminf(fmaxf(bp.y + of.y, 0.f), 224.f);
        float sr_, cr_;
        __sincosf(rot, &sr_, &cr_);                  // fast native trig
        float s1q = sc.x * sc.x;
        float s2q = sc.y * sc.y;
        float c00 = cr_*cr_*s1q + sr_*sr_*s2q + 1e-4f;
        float c01 = cr_*sr_*(s1q - s2q);
        float c11 = sr_*sr_*s1q + cr_*cr_*s2q + 1e-4f;
        // exact axis-aligned extents of the {dist <= 30} ellipse
        float rx = sqrtf(30.f * c00);
        float ry = sqrtf(30.f * c11);
        float rdet = 1.0f / (c00*c11 - c01*c01);
        float A =  K_EXP * c11 * rdet;
        float B = -2.0f * K_EXP * c01 * rdet;
        float C =  K_EXP * c00 * rdet;
        float qr = a * color[3*g];
        float qg = a * color[3*g+1];
        float qb = a * color[3*g+2];

        sr += qr; sg += qg; sb += qb;

        const bool hit = (cx - rx <= txmax) & (cx + rx >= txmin) &
                         (cy - ry <= tymax) & (cy + ry >= tymin);
        // wave-aggregated compaction: one LDS atomic per wave, not per hit
        const unsigned long long m = __ballot(hit);
        if (m) {
            int base = 0;
            if (lane == 0) base = atomicAdd(&cnt, __popcll(m));
            base = __shfl(base, 0);
            if (hit) {
                const int idx = base + __popcll(m & ((1ull << lane) - 1ull));
                list[2*idx]     = make_float4(cx, cy, A, B);
                list[2*idx + 1] = make_float4(C, qr, qg, qb);
            }
        }
    }

    // block reduction of background color sum
    #pragma unroll
    for (int o = 32; o >= 1; o >>= 1) {
        sr += __shfl_down(sr, o);
        sg += __shfl_down(sg, o);
        sb += __shfl_down(sb, o);
    }
    const int wid = tid >> 6;
    if (lane == 0) { sred[wid][0] = sr; sred[wid][1] = sg; sred[wid][2] = sb; }
    __syncthreads();

    const float S0 = sred[0][0] + sred[1][0] + sred[2][0] + sred[3][0];
    const float S1 = sred[0][1] + sred[1][1] + sred[2][1] + sred[3][1];
    const float S2 = sred[0][2] + sred[1][2] + sred[2][2] + sred[3][2];
    const int n = cnt;

    const int lx = tid & 15;
    const int ly = tid >> 4;
    const float px = (float)(bx0 + lx);
    const float py = (float)(by0 + ly);

    float r = W15 * S0;
    float g = W15 * S1;
    float b = W15 * S2;

    #pragma unroll 4
    for (int i = 0; i < n; ++i) {
        const float4 qa = list[2*i];        // wave-uniform -> LDS broadcast
        const float4 qc = list[2*i + 1];
        float dx = px - qa.x;
        float dy = py - qa.y;
        float e  = fmaf(dx, fmaf(qa.z, dx, qa.w * dy), qc.x * (dy * dy));
        e = fmaxf(e, ELIM);
        float w = __builtin_amdgcn_exp2f(e) - W15;   // cancels background exactly
        r = fmaf(w, qc.y, r);
        g = fmaf(w, qc.z, g);
        b = fmaf(w, qc.w, b);
    }

    const int p = (by0 + ly) * IMG_W + bx0 + lx;
    out[p]            = r;
    out[NPIX + p]     = g;
    out[2*NPIX + p]   = b;
}

extern "C" void kernel_launch(void* const* d_in, const int* in_sizes, int n_in,
                              void* d_out, int out_size, void* d_ws, size_t ws_size,
                              hipStream_t stream)
{
    const float* alpha    = (const float*)d_in[0];
    const float* color    = (const float*)d_in[1];
    const float* offset   = (const float*)d_in[2];
    const float* scale    = (const float*)d_in[3];
    const float* rotation = (const float*)d_in[4];
    const float* basep    = (const float*)d_in[5];
    const float* iw       = (const float*)d_in[6];
    float* out = (float*)d_out;

    fused_raster_kernel<<<dim3(TXN, TYN), 256, 0, stream>>>(
        alpha, color, offset, scale, rotation, basep, iw, out);
}